// Round 1
// baseline (2828.316 us; speedup 1.0000x reference)
//
#include <hip/hip_runtime.h>
#include <hip/hip_bf16.h>
#include <math.h>

// Problem constants (from reference)
#define BB 2
#define LL 2048
#define DMODEL 1024
#define DINNER 2048
#define DSTATE 16
#define DCONV 4
#define DTRANK 64
#define MROWS (BB * LL)          // 4096
#define XPROJ_N (DTRANK + 2 * DSTATE)  // 96

__device__ __forceinline__ float siluf(float x) {
    return x / (1.f + expf(-x));
}
__device__ __forceinline__ float softplusf(float x) {
    // numerically stable log1p(exp(x))
    return fmaxf(x, 0.f) + log1pf(expf(-fabsf(x)));
}

// -------------------------------------------------------------------------
// Generic fp32 GEMM: C[M,N] = act( A[M,K(lda)] @ B[N,K]^T + bias[N] )
// 64x64 tile, BK=16, 256 threads, 4x4 microtile per thread.
// Requires: M % 64 == 0, K % 16 == 0, N % 4 == 0, lda % 4 == 0.
// act: 0 = none, 1 = silu, 2 = softplus
// -------------------------------------------------------------------------
#define BM 64
#define BN 64
#define BK 16

__global__ __launch_bounds__(256) void gemm_abt(
    const float* __restrict__ A, const float* __restrict__ Bm,
    float* __restrict__ C, const float* __restrict__ bias,
    int M, int N, int K, int lda, int act)
{
    __shared__ __align__(16) float As[BK][BM];
    __shared__ __align__(16) float Bs[BK][BN];

    const int tid = threadIdx.x;
    const int bn = blockIdx.x, bm = blockIdx.y;
    const int tx = tid & 15, ty = tid >> 4;   // 16x16 thread grid
    const int lm = tid >> 2;                  // 0..63 : tile row loaded
    const int lk = (tid & 3) * 4;             // 0,4,8,12 : k sub-offset

    const int rowA = bm * BM + lm;            // always < M (M % 64 == 0)
    const int rowB = bn * BN + lm;

    float acc[4][4] = {};

    for (int k0 = 0; k0 < K; k0 += BK) {
        float4 av = *reinterpret_cast<const float4*>(&A[(size_t)rowA * lda + k0 + lk]);
        float4 bv = make_float4(0.f, 0.f, 0.f, 0.f);
        if (rowB < N)
            bv = *reinterpret_cast<const float4*>(&Bm[(size_t)rowB * K + k0 + lk]);
        As[lk + 0][lm] = av.x; As[lk + 1][lm] = av.y;
        As[lk + 2][lm] = av.z; As[lk + 3][lm] = av.w;
        Bs[lk + 0][lm] = bv.x; Bs[lk + 1][lm] = bv.y;
        Bs[lk + 2][lm] = bv.z; Bs[lk + 3][lm] = bv.w;
        __syncthreads();

        #pragma unroll
        for (int k = 0; k < BK; ++k) {
            const float4 a = *reinterpret_cast<const float4*>(&As[k][ty * 4]);
            const float4 b = *reinterpret_cast<const float4*>(&Bs[k][tx * 4]);
            const float ar[4] = {a.x, a.y, a.z, a.w};
            const float br[4] = {b.x, b.y, b.z, b.w};
            #pragma unroll
            for (int i = 0; i < 4; ++i)
                #pragma unroll
                for (int j = 0; j < 4; ++j)
                    acc[i][j] = fmaf(ar[i], br[j], acc[i][j]);
        }
        __syncthreads();
    }

    const int nbase = bn * BN + tx * 4;
    if (nbase < N) {   // N % 4 == 0 and nbase % 4 == 0 => all 4 cols valid
        #pragma unroll
        for (int i = 0; i < 4; ++i) {
            const int m = bm * BM + ty * 4 + i;
            float vv[4];
            #pragma unroll
            for (int j = 0; j < 4; ++j) {
                float t = acc[i][j];
                if (bias) t += bias[nbase + j];
                if (act == 1) t = siluf(t);
                else if (act == 2) t = softplusf(t);
                vv[j] = t;
            }
            *reinterpret_cast<float4*>(&C[(size_t)m * N + nbase]) =
                make_float4(vv[0], vv[1], vv[2], vv[3]);
        }
    }
}

// -------------------------------------------------------------------------
// Causal depthwise conv1d (W=4) + bias + SiLU.
// xin = xz[..., 0:DINNER] (row stride 2*DINNER), output xc compact.
// -------------------------------------------------------------------------
__global__ __launch_bounds__(256) void conv_silu_kernel(
    const float* __restrict__ xz, const float* __restrict__ w,
    const float* __restrict__ b, float* __restrict__ xc)
{
    const int idx = blockIdx.x * blockDim.x + threadIdx.x; // (bb*L + l)*DINNER + c
    const int c = idx % DINNER;
    const int bl = idx / DINNER;
    const int l = bl % LL;
    const int bb = bl / LL;
    if (bb >= BB) return;

    const float* xin = xz + (size_t)bb * LL * (2 * DINNER) + c;
    float acc = b[c];
    #pragma unroll
    for (int k = 0; k < DCONV; ++k) {
        const int ll = l - (DCONV - 1) + k;
        if (ll >= 0)
            acc = fmaf(xin[(size_t)ll * (2 * DINNER)], w[c * DCONV + k], acc);
    }
    xc[idx] = siluf(acc);
}

// -------------------------------------------------------------------------
// Selective scan. One 16-lane group per (b,d); lane = state index n.
// Fuses: h recurrence, y = <h,C> + D*u, gating y *= silu(z).
// Writes y in-place over xc (u is read before the write each iteration;
// the 16 lanes of a group are in one wave -> lockstep, safe).
// -------------------------------------------------------------------------
__global__ __launch_bounds__(256) void scan_kernel(
    const float* __restrict__ delta, const float* __restrict__ xdbl,
    float* __restrict__ xc, const float* __restrict__ xz,
    const float* __restrict__ A_log, const float* __restrict__ Dvec)
{
    const int tid = threadIdx.x;
    const int n = tid & 15;
    const int dloc = tid >> 4;               // 0..15
    const int d = blockIdx.x * 16 + dloc;
    const int b = blockIdx.y;

    const float A = -expf(A_log[d * DSTATE + n]);
    const float Dd = Dvec[d];

    const float* dp = delta + (size_t)b * LL * DINNER + d;
    float*       up = xc    + (size_t)b * LL * DINNER + d;
    const float* xb = xdbl  + (size_t)b * LL * XPROJ_N;
    const float* zp = xz    + (size_t)b * LL * (2 * DINNER) + DINNER + d;

    float h = 0.f;
    for (int t = 0; t < LL; ++t) {
        const float dl = dp[(size_t)t * DINNER];
        const float u  = up[(size_t)t * DINNER];
        const float Bn = xb[t * XPROJ_N + DTRANK + n];
        const float Cn = xb[t * XPROJ_N + DTRANK + DSTATE + n];

        h = expf(dl * A) * h + (dl * u) * Bn;
        float p = h * Cn;
        p += __shfl_xor(p, 1);
        p += __shfl_xor(p, 2);
        p += __shfl_xor(p, 4);
        p += __shfl_xor(p, 8);
        if (n == 0) {
            const float z = zp[(size_t)t * (2 * DINNER)];
            up[(size_t)t * DINNER] = (p + u * Dd) * siluf(z);
        }
    }
}

// -------------------------------------------------------------------------
extern "C" void kernel_launch(void* const* d_in, const int* in_sizes, int n_in,
                              void* d_out, int out_size, void* d_ws, size_t ws_size,
                              hipStream_t stream) {
    const float* x         = (const float*)d_in[0];
    const float* in_proj_w = (const float*)d_in[1];
    const float* conv_w    = (const float*)d_in[2];
    const float* conv_b    = (const float*)d_in[3];
    const float* x_proj_w  = (const float*)d_in[4];
    const float* dt_proj_w = (const float*)d_in[5];
    const float* dt_proj_b = (const float*)d_in[6];
    const float* A_log     = (const float*)d_in[7];
    const float* Dvec      = (const float*)d_in[8];
    const float* ssm_out_w = (const float*)d_in[9];
    const float* final_w   = (const float*)d_in[10];
    const float* final_b   = (const float*)d_in[11];
    float* out = (float*)d_out;

    // workspace layout (floats)
    float* ws    = (float*)d_ws;
    float* xz    = ws;                                    // 4096 x 4096
    float* xc    = xz   + (size_t)MROWS * (2 * DINNER);   // 4096 x 2048
    float* xdbl  = xc   + (size_t)MROWS * DINNER;         // 4096 x 96
    float* delta = xdbl + (size_t)MROWS * XPROJ_N;        // 4096 x 2048
    float* outb  = delta + (size_t)MROWS * DINNER;        // 4096 x 1024

    // 1) in_proj: xz = x @ in_proj_w^T   (M=4096, N=4096, K=1024)
    gemm_abt<<<dim3(2 * DINNER / BN, MROWS / BM), 256, 0, stream>>>(
        x, in_proj_w, xz, nullptr, MROWS, 2 * DINNER, DMODEL, DMODEL, 0);

    // 2) causal depthwise conv + SiLU -> xc
    conv_silu_kernel<<<(MROWS * DINNER) / 256, 256, 0, stream>>>(
        xz, conv_w, conv_b, xc);

    // 3) x_proj: xdbl = xc @ x_proj_w^T  (M=4096, N=96, K=2048)
    gemm_abt<<<dim3((XPROJ_N + BN - 1) / BN, MROWS / BM), 256, 0, stream>>>(
        xc, x_proj_w, xdbl, nullptr, MROWS, XPROJ_N, DINNER, DINNER, 0);

    // 4) delta = softplus(dt @ dt_proj_w^T + dt_proj_b)  (M=4096, N=2048, K=64, lda=96)
    gemm_abt<<<dim3(DINNER / BN, MROWS / BM), 256, 0, stream>>>(
        xdbl, dt_proj_w, delta, dt_proj_b, MROWS, DINNER, DTRANK, XPROJ_N, 2);

    // 5) selective scan + skip + gate (in-place y -> xc)
    scan_kernel<<<dim3(DINNER / 16, BB), 256, 0, stream>>>(
        delta, xdbl, xc, xz, A_log, Dvec);

    // 6) out_proj: outb = y @ ssm_out_w^T  (M=4096, N=1024, K=2048)
    gemm_abt<<<dim3(DMODEL / BN, MROWS / BM), 256, 0, stream>>>(
        xc, ssm_out_w, outb, nullptr, MROWS, DMODEL, DINNER, DINNER, 0);

    // 7) final: out = silu(outb @ final_w^T + final_b)  (M=4096, N=1024, K=1024)
    gemm_abt<<<dim3(DMODEL / BN, MROWS / BM), 256, 0, stream>>>(
        outb, final_w, out, final_b, MROWS, DMODEL, DMODEL, DMODEL, 1);
}

// Round 2
// 1294.539 us; speedup vs baseline: 2.1848x; 2.1848x over previous
//
#include <hip/hip_runtime.h>
#include <hip/hip_bf16.h>
#include <math.h>

// Problem constants (from reference)
#define BB 2
#define LL 2048
#define DMODEL 1024
#define DINNER 2048
#define DSTATE 16
#define DCONV 4
#define DTRANK 64
#define MROWS (BB * LL)          // 4096
#define XPROJ_N (DTRANK + 2 * DSTATE)  // 96

// scan segmentation
#define SEG 16
#define LS (LL / SEG)            // 128

__device__ __forceinline__ float siluf(float x) {
    return x / (1.f + expf(-x));
}
__device__ __forceinline__ float softplusf(float x) {
    return fmaxf(x, 0.f) + log1pf(expf(-fabsf(x)));
}

// -------------------------------------------------------------------------
// Generic fp32 GEMM: C[M,N] = act( A[M,K(lda)] @ B[N,K]^T + bias[N] )
// 64x64 tile, BK=16, 256 threads, 4x4 microtile per thread.
// act: 0 = none, 1 = silu, 2 = softplus
// -------------------------------------------------------------------------
#define BM 64
#define BN 64
#define BK 16

__global__ __launch_bounds__(256) void gemm_abt(
    const float* __restrict__ A, const float* __restrict__ Bm,
    float* __restrict__ C, const float* __restrict__ bias,
    int M, int N, int K, int lda, int act)
{
    __shared__ __align__(16) float As[BK][BM];
    __shared__ __align__(16) float Bs[BK][BN];

    const int tid = threadIdx.x;
    const int bn = blockIdx.x, bm = blockIdx.y;
    const int tx = tid & 15, ty = tid >> 4;   // 16x16 thread grid
    const int lm = tid >> 2;                  // 0..63 : tile row loaded
    const int lk = (tid & 3) * 4;             // 0,4,8,12 : k sub-offset

    const int rowA = bm * BM + lm;
    const int rowB = bn * BN + lm;

    float acc[4][4] = {};

    for (int k0 = 0; k0 < K; k0 += BK) {
        float4 av = *reinterpret_cast<const float4*>(&A[(size_t)rowA * lda + k0 + lk]);
        float4 bv = make_float4(0.f, 0.f, 0.f, 0.f);
        if (rowB < N)
            bv = *reinterpret_cast<const float4*>(&Bm[(size_t)rowB * K + k0 + lk]);
        As[lk + 0][lm] = av.x; As[lk + 1][lm] = av.y;
        As[lk + 2][lm] = av.z; As[lk + 3][lm] = av.w;
        Bs[lk + 0][lm] = bv.x; Bs[lk + 1][lm] = bv.y;
        Bs[lk + 2][lm] = bv.z; Bs[lk + 3][lm] = bv.w;
        __syncthreads();

        #pragma unroll
        for (int k = 0; k < BK; ++k) {
            const float4 a = *reinterpret_cast<const float4*>(&As[k][ty * 4]);
            const float4 b = *reinterpret_cast<const float4*>(&Bs[k][tx * 4]);
            const float ar[4] = {a.x, a.y, a.z, a.w};
            const float br[4] = {b.x, b.y, b.z, b.w};
            #pragma unroll
            for (int i = 0; i < 4; ++i)
                #pragma unroll
                for (int j = 0; j < 4; ++j)
                    acc[i][j] = fmaf(ar[i], br[j], acc[i][j]);
        }
        __syncthreads();
    }

    const int nbase = bn * BN + tx * 4;
    if (nbase < N) {
        #pragma unroll
        for (int i = 0; i < 4; ++i) {
            const int m = bm * BM + ty * 4 + i;
            float vv[4];
            #pragma unroll
            for (int j = 0; j < 4; ++j) {
                float t = acc[i][j];
                if (bias) t += bias[nbase + j];
                if (act == 1) t = siluf(t);
                else if (act == 2) t = softplusf(t);
                vv[j] = t;
            }
            *reinterpret_cast<float4*>(&C[(size_t)m * N + nbase]) =
                make_float4(vv[0], vv[1], vv[2], vv[3]);
        }
    }
}

// -------------------------------------------------------------------------
// Causal depthwise conv1d (W=4) + bias + SiLU.
// -------------------------------------------------------------------------
__global__ __launch_bounds__(256) void conv_silu_kernel(
    const float* __restrict__ xz, const float* __restrict__ w,
    const float* __restrict__ b, float* __restrict__ xc)
{
    const int idx = blockIdx.x * blockDim.x + threadIdx.x;
    const int c = idx % DINNER;
    const int bl = idx / DINNER;
    const int l = bl % LL;
    const int bb = bl / LL;
    if (bb >= BB) return;

    const float* xin = xz + (size_t)bb * LL * (2 * DINNER) + c;
    float acc = b[c];
    #pragma unroll
    for (int k = 0; k < DCONV; ++k) {
        const int ll = l - (DCONV - 1) + k;
        if (ll >= 0)
            acc = fmaf(xin[(size_t)ll * (2 * DINNER)], w[c * DCONV + k], acc);
    }
    xc[idx] = siluf(acc);
}

// -------------------------------------------------------------------------
// Segmented selective scan.
// Diagonal linear recurrence h_t = a_t h_{t-1} + b_t, with
// a_t = exp(dl_t * A[n])  =>  segment decay = exp(A[n] * sum(dl)).
//
// Pass A: per (b, seg, d) thread, h[16] in registers, local scan from 0.
//         Emits h_local_end[16] and decay[16], layout [b][seg][n][d]
//         (d fastest -> coalesced).
// Pass B: per (b, d, n) thread, sequential combine over SEG segments ->
//         true h_start per segment.
// Pass C: per (b, seg, d) thread, re-scan from true h_start, fuse
//         y = <h,C> + D*u and y *= silu(z); writes y over xc in place.
// -------------------------------------------------------------------------
__global__ __launch_bounds__(256) void scan_part1(
    const float* __restrict__ delta, const float* __restrict__ xdbl,
    const float* __restrict__ xc, const float* __restrict__ A_log,
    float* __restrict__ hloc, float* __restrict__ decay)
{
    const int d = blockIdx.x * 256 + threadIdx.x;
    const int seg = blockIdx.y;
    const int b = blockIdx.z;
    const int t0 = seg * LS;

    float Ad[DSTATE];
    #pragma unroll
    for (int n = 0; n < DSTATE; ++n)
        Ad[n] = -expf(A_log[d * DSTATE + n]);

    float h[DSTATE];
    #pragma unroll
    for (int n = 0; n < DSTATE; ++n) h[n] = 0.f;

    const float* dp = delta + ((size_t)b * LL) * DINNER + d;
    const float* up = xc    + ((size_t)b * LL) * DINNER + d;
    const float* xb = xdbl  + ((size_t)b * LL) * XPROJ_N;

    float sum_dl = 0.f;
    for (int t = t0; t < t0 + LS; ++t) {
        const float dl = dp[(size_t)t * DINNER];
        const float u  = up[(size_t)t * DINNER];
        const float4 b0 = *reinterpret_cast<const float4*>(&xb[t * XPROJ_N + DTRANK + 0]);
        const float4 b1 = *reinterpret_cast<const float4*>(&xb[t * XPROJ_N + DTRANK + 4]);
        const float4 b2 = *reinterpret_cast<const float4*>(&xb[t * XPROJ_N + DTRANK + 8]);
        const float4 b3 = *reinterpret_cast<const float4*>(&xb[t * XPROJ_N + DTRANK + 12]);
        const float Bv[DSTATE] = {b0.x, b0.y, b0.z, b0.w, b1.x, b1.y, b1.z, b1.w,
                                  b2.x, b2.y, b2.z, b2.w, b3.x, b3.y, b3.z, b3.w};
        const float dlu = dl * u;
        sum_dl += dl;
        #pragma unroll
        for (int n = 0; n < DSTATE; ++n)
            h[n] = __expf(dl * Ad[n]) * h[n] + dlu * Bv[n];
    }

    const size_t base = (((size_t)b * SEG + seg) * DSTATE) * DINNER + d;
    #pragma unroll
    for (int n = 0; n < DSTATE; ++n) {
        hloc[base + (size_t)n * DINNER]  = h[n];
        decay[base + (size_t)n * DINNER] = __expf(Ad[n] * sum_dl);
    }
}

__global__ __launch_bounds__(256) void scan_combine(
    const float* __restrict__ hloc, const float* __restrict__ decay,
    float* __restrict__ hstart)
{
    const int idx = blockIdx.x * 256 + threadIdx.x;   // b*16*DINNER + n*DINNER + d
    const int d = idx % DINNER;
    const int n = (idx / DINNER) % DSTATE;
    const int b = idx / (DINNER * DSTATE);
    if (b >= BB) return;

    float carry = 0.f;
    for (int s = 0; s < SEG; ++s) {
        const size_t off = (((size_t)b * SEG + s) * DSTATE + n) * DINNER + d;
        hstart[off] = carry;
        carry = decay[off] * carry + hloc[off];
    }
}

__global__ __launch_bounds__(256) void scan_part2(
    const float* __restrict__ delta, const float* __restrict__ xdbl,
    float* __restrict__ xc, const float* __restrict__ xz,
    const float* __restrict__ A_log, const float* __restrict__ Dvec,
    const float* __restrict__ hstart)
{
    const int d = blockIdx.x * 256 + threadIdx.x;
    const int seg = blockIdx.y;
    const int b = blockIdx.z;
    const int t0 = seg * LS;

    float Ad[DSTATE];
    #pragma unroll
    for (int n = 0; n < DSTATE; ++n)
        Ad[n] = -expf(A_log[d * DSTATE + n]);

    float h[DSTATE];
    const size_t hbase = (((size_t)b * SEG + seg) * DSTATE) * DINNER + d;
    #pragma unroll
    for (int n = 0; n < DSTATE; ++n)
        h[n] = hstart[hbase + (size_t)n * DINNER];

    const float Dd = Dvec[d];
    const float* dp = delta + ((size_t)b * LL) * DINNER + d;
    float*       up = xc    + ((size_t)b * LL) * DINNER + d;
    const float* xb = xdbl  + ((size_t)b * LL) * XPROJ_N;
    const float* zp = xz    + ((size_t)b * LL) * (2 * DINNER) + DINNER + d;

    for (int t = t0; t < t0 + LS; ++t) {
        const float dl = dp[(size_t)t * DINNER];
        const float u  = up[(size_t)t * DINNER];
        const float z  = zp[(size_t)t * (2 * DINNER)];
        const float4 b0 = *reinterpret_cast<const float4*>(&xb[t * XPROJ_N + DTRANK + 0]);
        const float4 b1 = *reinterpret_cast<const float4*>(&xb[t * XPROJ_N + DTRANK + 4]);
        const float4 b2 = *reinterpret_cast<const float4*>(&xb[t * XPROJ_N + DTRANK + 8]);
        const float4 b3 = *reinterpret_cast<const float4*>(&xb[t * XPROJ_N + DTRANK + 12]);
        const float4 c0 = *reinterpret_cast<const float4*>(&xb[t * XPROJ_N + DTRANK + DSTATE + 0]);
        const float4 c1 = *reinterpret_cast<const float4*>(&xb[t * XPROJ_N + DTRANK + DSTATE + 4]);
        const float4 c2 = *reinterpret_cast<const float4*>(&xb[t * XPROJ_N + DTRANK + DSTATE + 8]);
        const float4 c3 = *reinterpret_cast<const float4*>(&xb[t * XPROJ_N + DTRANK + DSTATE + 12]);
        const float Bv[DSTATE] = {b0.x, b0.y, b0.z, b0.w, b1.x, b1.y, b1.z, b1.w,
                                  b2.x, b2.y, b2.z, b2.w, b3.x, b3.y, b3.z, b3.w};
        const float Cv[DSTATE] = {c0.x, c0.y, c0.z, c0.w, c1.x, c1.y, c1.z, c1.w,
                                  c2.x, c2.y, c2.z, c2.w, c3.x, c3.y, c3.z, c3.w};
        const float dlu = dl * u;
        float y = 0.f;
        #pragma unroll
        for (int n = 0; n < DSTATE; ++n) {
            h[n] = __expf(dl * Ad[n]) * h[n] + dlu * Bv[n];
            y = fmaf(h[n], Cv[n], y);
        }
        up[(size_t)t * DINNER] = (y + u * Dd) * siluf(z);
    }
}

// -------------------------------------------------------------------------
extern "C" void kernel_launch(void* const* d_in, const int* in_sizes, int n_in,
                              void* d_out, int out_size, void* d_ws, size_t ws_size,
                              hipStream_t stream) {
    const float* x         = (const float*)d_in[0];
    const float* in_proj_w = (const float*)d_in[1];
    const float* conv_w    = (const float*)d_in[2];
    const float* conv_b    = (const float*)d_in[3];
    const float* x_proj_w  = (const float*)d_in[4];
    const float* dt_proj_w = (const float*)d_in[5];
    const float* dt_proj_b = (const float*)d_in[6];
    const float* A_log     = (const float*)d_in[7];
    const float* Dvec      = (const float*)d_in[8];
    const float* ssm_out_w = (const float*)d_in[9];
    const float* final_w   = (const float*)d_in[10];
    const float* final_b   = (const float*)d_in[11];
    float* out = (float*)d_out;

    // workspace layout (floats)
    float* ws    = (float*)d_ws;
    float* xz    = ws;                                    // 4096 x 4096
    float* xc    = xz   + (size_t)MROWS * (2 * DINNER);   // 4096 x 2048
    float* xdbl  = xc   + (size_t)MROWS * DINNER;         // 4096 x 96
    float* delta = xdbl + (size_t)MROWS * XPROJ_N;        // 4096 x 2048
    float* outb  = delta + (size_t)MROWS * DINNER;        // 4096 x 1024

    // scan scratch overlaid on outb (dead until step 6):
    // 3 arrays of B*SEG*16*DINNER floats = 3 * 4 MB <= 16 MB of outb
    float* hloc   = outb;
    float* decay  = hloc  + (size_t)BB * SEG * DSTATE * DINNER;
    float* hstart = decay + (size_t)BB * SEG * DSTATE * DINNER;

    // 1) in_proj: xz = x @ in_proj_w^T   (M=4096, N=4096, K=1024)
    gemm_abt<<<dim3(2 * DINNER / BN, MROWS / BM), 256, 0, stream>>>(
        x, in_proj_w, xz, nullptr, MROWS, 2 * DINNER, DMODEL, DMODEL, 0);

    // 2) causal depthwise conv + SiLU -> xc
    conv_silu_kernel<<<(MROWS * DINNER) / 256, 256, 0, stream>>>(
        xz, conv_w, conv_b, xc);

    // 3) x_proj: xdbl = xc @ x_proj_w^T  (M=4096, N=96, K=2048)
    gemm_abt<<<dim3((XPROJ_N + BN - 1) / BN, MROWS / BM), 256, 0, stream>>>(
        xc, x_proj_w, xdbl, nullptr, MROWS, XPROJ_N, DINNER, DINNER, 0);

    // 4) delta = softplus(dt @ dt_proj_w^T + dt_proj_b)  (M=4096, N=2048, K=64, lda=96)
    gemm_abt<<<dim3(DINNER / BN, MROWS / BM), 256, 0, stream>>>(
        xdbl, dt_proj_w, delta, dt_proj_b, MROWS, DINNER, DTRANK, XPROJ_N, 2);

    // 5) segmented selective scan + skip + gate (in-place y -> xc)
    scan_part1<<<dim3(DINNER / 256, SEG, BB), 256, 0, stream>>>(
        delta, xdbl, xc, A_log, hloc, decay);
    scan_combine<<<(BB * DSTATE * DINNER) / 256, 256, 0, stream>>>(
        hloc, decay, hstart);
    scan_part2<<<dim3(DINNER / 256, SEG, BB), 256, 0, stream>>>(
        delta, xdbl, xc, xz, A_log, Dvec, hstart);

    // 6) out_proj: outb = y @ ssm_out_w^T  (M=4096, N=1024, K=2048)
    gemm_abt<<<dim3(DMODEL / BN, MROWS / BM), 256, 0, stream>>>(
        xc, ssm_out_w, outb, nullptr, MROWS, DMODEL, DINNER, DINNER, 0);

    // 7) final: out = silu(outb @ final_w^T + final_b)  (M=4096, N=1024, K=1024)
    gemm_abt<<<dim3(DMODEL / BN, MROWS / BM), 256, 0, stream>>>(
        outb, final_w, out, final_b, MROWS, DMODEL, DMODEL, DMODEL, 1);
}

// Round 3
// 605.940 us; speedup vs baseline: 4.6677x; 2.1364x over previous
//
#include <hip/hip_runtime.h>
#include <hip/hip_bf16.h>
#include <math.h>

// Problem constants (from reference)
#define BB 2
#define LL 2048
#define DMODEL 1024
#define DINNER 2048
#define DSTATE 16
#define DCONV 4
#define DTRANK 64
#define MROWS (BB * LL)          // 4096
#define XPROJ_N (DTRANK + 2 * DSTATE)  // 96

// scan segmentation
#define SEG 16
#define LS (LL / SEG)            // 128

typedef unsigned short ushort_t;
typedef short s8v __attribute__((ext_vector_type(8)));   // 8 x bf16 (4 VGPRs)
typedef float f4v __attribute__((ext_vector_type(4)));   // 4 x fp32 acc

__device__ __forceinline__ float siluf(float x) {
    return x / (1.f + expf(-x));
}
__device__ __forceinline__ float softplusf(float x) {
    return fmaxf(x, 0.f) + log1pf(expf(-fabsf(x)));
}
__device__ __forceinline__ ushort_t f32_to_bf16(float f) {
    unsigned u = __builtin_bit_cast(unsigned, f);
    unsigned r = (u + 0x7FFFu + ((u >> 16) & 1u)) >> 16;   // RNE
    return (ushort_t)r;
}

// -------------------------------------------------------------------------
// cast fp32 -> bf16, 4 elems/thread
// -------------------------------------------------------------------------
__global__ __launch_bounds__(256) void cast_bf16_kernel(
    const float* __restrict__ in, ushort_t* __restrict__ outp, int n)
{
    const int i = (blockIdx.x * 256 + threadIdx.x) * 4;
    if (i >= n) return;
    const float4 v = *reinterpret_cast<const float4*>(in + i);
    ushort_t o[4] = {f32_to_bf16(v.x), f32_to_bf16(v.y),
                     f32_to_bf16(v.z), f32_to_bf16(v.w)};
    *reinterpret_cast<uint2*>(outp + i) =
        *reinterpret_cast<uint2*>(o);
}

// -------------------------------------------------------------------------
// bf16 MFMA GEMM: C[M,N] = act( A[M,K] @ B[N,K]^T + bias[N] )
// 128x128 tile, BK=32, 256 threads = 4 waves, each wave 64x64 via 4x4
// mfma_f32_16x16x32_bf16. global_load_lds width-16 staging (m97 structure).
// Split output: cols >= splitN go to C1 at (col - splitN). store_bf16
// selects f32 vs bf16 output element type.
// -------------------------------------------------------------------------
#define TM 128
#define TN 128
#define TBK 32

__global__ __launch_bounds__(256) void gemm_bf16_mfma(
    const ushort_t* __restrict__ A, int lda,
    const ushort_t* __restrict__ B, int ldb,
    int K,
    void* __restrict__ C0v, void* __restrict__ C1v, int splitN, int ldc,
    const float* __restrict__ bias, int act, int store_bf16)
{
    __shared__ __align__(16) ushort_t As[TM * TBK];   // 8 KB
    __shared__ __align__(16) ushort_t Bs[TN * TBK];   // 8 KB

    const int tid  = threadIdx.x;
    const int lane = tid & 63;
    const int w    = tid >> 6;            // wave 0..3
    const int wm   = w & 1, wn = w >> 1;  // 2x2 wave grid
    const int m0   = blockIdx.y * TM;
    const int n0   = blockIdx.x * TN;

    // staging: per-lane source row/col within a 16-row chunk
    const int srow = lane >> 2;           // 0..15
    const int scol = (lane & 3) * 8;      // bf16 elems: 0,8,16,24

    f4v acc[4][4] = {};

    for (int k0 = 0; k0 < K; k0 += TBK) {
        #pragma unroll
        for (int t = 0; t < 2; ++t) {
            const int i = w * 2 + t;      // chunk 0..7 -> rows i*16..i*16+15
            const ushort_t* ga = A + (size_t)(m0 + i * 16 + srow) * lda + k0 + scol;
            __builtin_amdgcn_global_load_lds(
                (const __attribute__((address_space(1))) unsigned int*)ga,
                (__attribute__((address_space(3))) unsigned int*)(As + i * 512),
                16, 0, 0);
            const ushort_t* gb = B + (size_t)(n0 + i * 16 + srow) * ldb + k0 + scol;
            __builtin_amdgcn_global_load_lds(
                (const __attribute__((address_space(1))) unsigned int*)gb,
                (__attribute__((address_space(3))) unsigned int*)(Bs + i * 512),
                16, 0, 0);
        }
        __syncthreads();

        const int fr = lane & 15;
        const int kg = lane >> 4;         // k-group 0..3 (8 elems each)
        s8v a[4], b[4];
        #pragma unroll
        for (int t = 0; t < 4; ++t) {
            a[t] = *reinterpret_cast<const s8v*>(As + (wm * 64 + t * 16 + fr) * TBK + kg * 8);
            b[t] = *reinterpret_cast<const s8v*>(Bs + (wn * 64 + t * 16 + fr) * TBK + kg * 8);
        }
        #pragma unroll
        for (int i = 0; i < 4; ++i)
            #pragma unroll
            for (int j = 0; j < 4; ++j)
                acc[i][j] = __builtin_amdgcn_mfma_f32_16x16x32_bf16(
                    a[i], b[j], acc[i][j], 0, 0, 0);
        __syncthreads();
    }

    // epilogue: C/D layout col=lane&15, row=(lane>>4)*4+reg  [m89]
    const int rbase = (lane >> 4) * 4;
    const int cbase = lane & 15;
    #pragma unroll
    for (int i = 0; i < 4; ++i) {
        #pragma unroll
        for (int j = 0; j < 4; ++j) {
            const int row = m0 + wm * 64 + i * 16 + rbase;
            const int col = n0 + wn * 64 + j * 16 + cbase;
            void* Cp = C0v;
            int c2 = col;
            if (C1v && col >= splitN) { Cp = C1v; c2 = col - splitN; }
            const float bv = bias ? bias[col] : 0.f;
            #pragma unroll
            for (int r = 0; r < 4; ++r) {
                float v = acc[i][j][r] + bv;
                if (act == 1) v = siluf(v);
                if (store_bf16)
                    ((ushort_t*)Cp)[(size_t)(row + r) * ldc + c2] = f32_to_bf16(v);
                else
                    ((float*)Cp)[(size_t)(row + r) * ldc + c2] = v;
            }
        }
    }
}

// -------------------------------------------------------------------------
// fp32 vector GEMM (kept for the small, accuracy-sensitive delta path):
// C[M,N] = act( A[M,K(lda)] @ B[N,K]^T + bias[N] ); act 0=none,2=softplus
// -------------------------------------------------------------------------
#define BM 64
#define BN 64
#define BK 16

__global__ __launch_bounds__(256) void gemm_abt(
    const float* __restrict__ A, const float* __restrict__ Bm,
    float* __restrict__ C, const float* __restrict__ bias,
    int M, int N, int K, int lda, int act)
{
    __shared__ __align__(16) float As[BK][BM];
    __shared__ __align__(16) float Bs[BK][BN];

    const int tid = threadIdx.x;
    const int bn = blockIdx.x, bm = blockIdx.y;
    const int tx = tid & 15, ty = tid >> 4;
    const int lm = tid >> 2;
    const int lk = (tid & 3) * 4;

    const int rowA = bm * BM + lm;
    const int rowB = bn * BN + lm;

    float acc[4][4] = {};

    for (int k0 = 0; k0 < K; k0 += BK) {
        float4 av = *reinterpret_cast<const float4*>(&A[(size_t)rowA * lda + k0 + lk]);
        float4 bv = make_float4(0.f, 0.f, 0.f, 0.f);
        if (rowB < N)
            bv = *reinterpret_cast<const float4*>(&Bm[(size_t)rowB * K + k0 + lk]);
        As[lk + 0][lm] = av.x; As[lk + 1][lm] = av.y;
        As[lk + 2][lm] = av.z; As[lk + 3][lm] = av.w;
        Bs[lk + 0][lm] = bv.x; Bs[lk + 1][lm] = bv.y;
        Bs[lk + 2][lm] = bv.z; Bs[lk + 3][lm] = bv.w;
        __syncthreads();

        #pragma unroll
        for (int k = 0; k < BK; ++k) {
            const float4 a = *reinterpret_cast<const float4*>(&As[k][ty * 4]);
            const float4 b = *reinterpret_cast<const float4*>(&Bs[k][tx * 4]);
            const float ar[4] = {a.x, a.y, a.z, a.w};
            const float br[4] = {b.x, b.y, b.z, b.w};
            #pragma unroll
            for (int i = 0; i < 4; ++i)
                #pragma unroll
                for (int j = 0; j < 4; ++j)
                    acc[i][j] = fmaf(ar[i], br[j], acc[i][j]);
        }
        __syncthreads();
    }

    const int nbase = bn * BN + tx * 4;
    if (nbase < N) {
        #pragma unroll
        for (int i = 0; i < 4; ++i) {
            const int m = bm * BM + ty * 4 + i;
            float vv[4];
            #pragma unroll
            for (int j = 0; j < 4; ++j) {
                float t = acc[i][j];
                if (bias) t += bias[nbase + j];
                if (act == 2) t = softplusf(t);
                vv[j] = t;
            }
            *reinterpret_cast<float4*>(&C[(size_t)m * N + nbase]) =
                make_float4(vv[0], vv[1], vv[2], vv[3]);
        }
    }
}

// -------------------------------------------------------------------------
// Causal depthwise conv1d (W=4) + bias + SiLU. xin compact (ld = DINNER).
// -------------------------------------------------------------------------
__global__ __launch_bounds__(256) void conv_silu_kernel(
    const float* __restrict__ xin, const float* __restrict__ w,
    const float* __restrict__ b, float* __restrict__ xc)
{
    const int idx = blockIdx.x * blockDim.x + threadIdx.x;
    const int c = idx % DINNER;
    const int bl = idx / DINNER;
    const int l = bl % LL;
    const int bb = bl / LL;
    if (bb >= BB) return;

    const float* xp = xin + (size_t)bb * LL * DINNER + c;
    float acc = b[c];
    #pragma unroll
    for (int k = 0; k < DCONV; ++k) {
        const int ll = l - (DCONV - 1) + k;
        if (ll >= 0)
            acc = fmaf(xp[(size_t)ll * DINNER], w[c * DCONV + k], acc);
    }
    xc[idx] = siluf(acc);
}

// -------------------------------------------------------------------------
// Segmented selective scan (see round-1 notes). part2 now reads z from the
// compact z buffer and writes y as bf16 (feeds the out_proj MFMA GEMM).
// -------------------------------------------------------------------------
__global__ __launch_bounds__(256) void scan_part1(
    const float* __restrict__ delta, const float* __restrict__ xdbl,
    const float* __restrict__ xc, const float* __restrict__ A_log,
    float* __restrict__ hloc, float* __restrict__ decay)
{
    const int d = blockIdx.x * 256 + threadIdx.x;
    const int seg = blockIdx.y;
    const int b = blockIdx.z;
    const int t0 = seg * LS;

    float Ad[DSTATE];
    #pragma unroll
    for (int n = 0; n < DSTATE; ++n)
        Ad[n] = -expf(A_log[d * DSTATE + n]);

    float h[DSTATE];
    #pragma unroll
    for (int n = 0; n < DSTATE; ++n) h[n] = 0.f;

    const float* dp = delta + ((size_t)b * LL) * DINNER + d;
    const float* up = xc    + ((size_t)b * LL) * DINNER + d;
    const float* xb = xdbl  + ((size_t)b * LL) * XPROJ_N;

    float sum_dl = 0.f;
    for (int t = t0; t < t0 + LS; ++t) {
        const float dl = dp[(size_t)t * DINNER];
        const float u  = up[(size_t)t * DINNER];
        const float4 b0 = *reinterpret_cast<const float4*>(&xb[t * XPROJ_N + DTRANK + 0]);
        const float4 b1 = *reinterpret_cast<const float4*>(&xb[t * XPROJ_N + DTRANK + 4]);
        const float4 b2 = *reinterpret_cast<const float4*>(&xb[t * XPROJ_N + DTRANK + 8]);
        const float4 b3 = *reinterpret_cast<const float4*>(&xb[t * XPROJ_N + DTRANK + 12]);
        const float Bv[DSTATE] = {b0.x, b0.y, b0.z, b0.w, b1.x, b1.y, b1.z, b1.w,
                                  b2.x, b2.y, b2.z, b2.w, b3.x, b3.y, b3.z, b3.w};
        const float dlu = dl * u;
        sum_dl += dl;
        #pragma unroll
        for (int n = 0; n < DSTATE; ++n)
            h[n] = __expf(dl * Ad[n]) * h[n] + dlu * Bv[n];
    }

    const size_t base = (((size_t)b * SEG + seg) * DSTATE) * DINNER + d;
    #pragma unroll
    for (int n = 0; n < DSTATE; ++n) {
        hloc[base + (size_t)n * DINNER]  = h[n];
        decay[base + (size_t)n * DINNER] = __expf(Ad[n] * sum_dl);
    }
}

__global__ __launch_bounds__(256) void scan_combine(
    const float* __restrict__ hloc, const float* __restrict__ decay,
    float* __restrict__ hstart)
{
    const int idx = blockIdx.x * 256 + threadIdx.x;
    const int d = idx % DINNER;
    const int n = (idx / DINNER) % DSTATE;
    const int b = idx / (DINNER * DSTATE);
    if (b >= BB) return;

    float carry = 0.f;
    for (int s = 0; s < SEG; ++s) {
        const size_t off = (((size_t)b * SEG + s) * DSTATE + n) * DINNER + d;
        hstart[off] = carry;
        carry = decay[off] * carry + hloc[off];
    }
}

__global__ __launch_bounds__(256) void scan_part2(
    const float* __restrict__ delta, const float* __restrict__ xdbl,
    const float* __restrict__ xc, const float* __restrict__ z,
    const float* __restrict__ A_log, const float* __restrict__ Dvec,
    const float* __restrict__ hstart, ushort_t* __restrict__ ybf)
{
    const int d = blockIdx.x * 256 + threadIdx.x;
    const int seg = blockIdx.y;
    const int b = blockIdx.z;
    const int t0 = seg * LS;

    float Ad[DSTATE];
    #pragma unroll
    for (int n = 0; n < DSTATE; ++n)
        Ad[n] = -expf(A_log[d * DSTATE + n]);

    float h[DSTATE];
    const size_t hbase = (((size_t)b * SEG + seg) * DSTATE) * DINNER + d;
    #pragma unroll
    for (int n = 0; n < DSTATE; ++n)
        h[n] = hstart[hbase + (size_t)n * DINNER];

    const float Dd = Dvec[d];
    const float* dp = delta + ((size_t)b * LL) * DINNER + d;
    const float* up = xc    + ((size_t)b * LL) * DINNER + d;
    const float* xb = xdbl  + ((size_t)b * LL) * XPROJ_N;
    const float* zp = z     + ((size_t)b * LL) * DINNER + d;
    ushort_t*    yp = ybf   + ((size_t)b * LL) * DINNER + d;

    for (int t = t0; t < t0 + LS; ++t) {
        const float dl = dp[(size_t)t * DINNER];
        const float u  = up[(size_t)t * DINNER];
        const float zv = zp[(size_t)t * DINNER];
        const float4 b0 = *reinterpret_cast<const float4*>(&xb[t * XPROJ_N + DTRANK + 0]);
        const float4 b1 = *reinterpret_cast<const float4*>(&xb[t * XPROJ_N + DTRANK + 4]);
        const float4 b2 = *reinterpret_cast<const float4*>(&xb[t * XPROJ_N + DTRANK + 8]);
        const float4 b3 = *reinterpret_cast<const float4*>(&xb[t * XPROJ_N + DTRANK + 12]);
        const float4 c0 = *reinterpret_cast<const float4*>(&xb[t * XPROJ_N + DTRANK + DSTATE + 0]);
        const float4 c1 = *reinterpret_cast<const float4*>(&xb[t * XPROJ_N + DTRANK + DSTATE + 4]);
        const float4 c2 = *reinterpret_cast<const float4*>(&xb[t * XPROJ_N + DTRANK + DSTATE + 8]);
        const float4 c3 = *reinterpret_cast<const float4*>(&xb[t * XPROJ_N + DTRANK + DSTATE + 12]);
        const float Bv[DSTATE] = {b0.x, b0.y, b0.z, b0.w, b1.x, b1.y, b1.z, b1.w,
                                  b2.x, b2.y, b2.z, b2.w, b3.x, b3.y, b3.z, b3.w};
        const float Cv[DSTATE] = {c0.x, c0.y, c0.z, c0.w, c1.x, c1.y, c1.z, c1.w,
                                  c2.x, c2.y, c2.z, c2.w, c3.x, c3.y, c3.z, c3.w};
        const float dlu = dl * u;
        float y = 0.f;
        #pragma unroll
        for (int n = 0; n < DSTATE; ++n) {
            h[n] = __expf(dl * Ad[n]) * h[n] + dlu * Bv[n];
            y = fmaf(h[n], Cv[n], y);
        }
        yp[(size_t)t * DINNER] = f32_to_bf16((y + u * Dd) * siluf(zv));
    }
}

// -------------------------------------------------------------------------
extern "C" void kernel_launch(void* const* d_in, const int* in_sizes, int n_in,
                              void* d_out, int out_size, void* d_ws, size_t ws_size,
                              hipStream_t stream) {
    const float* x         = (const float*)d_in[0];
    const float* in_proj_w = (const float*)d_in[1];
    const float* conv_w    = (const float*)d_in[2];
    const float* conv_b    = (const float*)d_in[3];
    const float* x_proj_w  = (const float*)d_in[4];
    const float* dt_proj_w = (const float*)d_in[5];
    const float* dt_proj_b = (const float*)d_in[6];
    const float* A_log     = (const float*)d_in[7];
    const float* Dvec      = (const float*)d_in[8];
    const float* ssm_out_w = (const float*)d_in[9];
    const float* final_w   = (const float*)d_in[10];
    const float* final_b   = (const float*)d_in[11];
    float* out = (float*)d_out;

    // ---- workspace layout (142 MB total) ----
    const size_t MB = 1024 * 1024;
    char* base = (char*)d_ws;
    float* xin   = (float*)(base);             // 32 MB [live: in_proj -> conv]
    float* z     = (float*)(base + 32 * MB);   // 32 MB [in_proj -> scan_part2]
    float* xc    = (float*)(base + 64 * MB);   // 32 MB [conv -> scan_part2]
    float* xdbl  = (float*)(base + 96 * MB);   // 1.5 MB [x_proj -> scan]
    float* delta = (float*)(base + 98 * MB);   // 32 MB [dt_proj -> scan_part2]
    float* hloc  = (float*)(base + 130 * MB);  // 4 MB scan scratch
    float* decay = (float*)(base + 134 * MB);  // 4 MB
    float* hstart= (float*)(base + 138 * MB);  // 4 MB
    // overlays on delta (dead until dt_proj):
    ushort_t* x_bf   = (ushort_t*)(base + 98 * MB);        // 8 MB [-> in_proj]
    ushort_t* ipw_bf = (ushort_t*)(base + 106 * MB);       // 8 MB [-> in_proj]
    // overlays on xin (dead after conv):
    ushort_t* y_bf    = (ushort_t*)(base);                 // 16 MB [scan_part2 -> out_proj]
    ushort_t* outb_bf = (ushort_t*)(base + 16 * MB);       // 8 MB [out_proj -> final]
    ushort_t* sow_bf  = (ushort_t*)(base + 24 * MB);       // 4 MB [cast(after conv) -> out_proj]
    ushort_t* fw_bf   = (ushort_t*)(base + 28 * MB);       // 2 MB [cast(after conv) -> final]

    // 0) casts for in_proj
    cast_bf16_kernel<<<(MROWS * DMODEL / 4) / 256, 256, 0, stream>>>(x, x_bf, MROWS * DMODEL);
    cast_bf16_kernel<<<(2 * DINNER * DMODEL / 4) / 256, 256, 0, stream>>>(in_proj_w, ipw_bf, 2 * DINNER * DMODEL);

    // 1) in_proj (bf16 MFMA): [xin | z] = x @ in_proj_w^T  (M=4096,N=4096,K=1024)
    gemm_bf16_mfma<<<dim3(2 * DINNER / TN, MROWS / TM), 256, 0, stream>>>(
        x_bf, DMODEL, ipw_bf, DMODEL, DMODEL,
        xin, z, DINNER, DINNER, nullptr, 0, 0);

    // 2) causal depthwise conv + SiLU -> xc (fp32)
    conv_silu_kernel<<<(MROWS * DINNER) / 256, 256, 0, stream>>>(xin, conv_w, conv_b, xc);

    // 2b) weight casts for steps 6/7 (xin region now dead)
    cast_bf16_kernel<<<(DMODEL * DINNER / 4) / 256, 256, 0, stream>>>(ssm_out_w, sow_bf, DMODEL * DINNER);
    cast_bf16_kernel<<<(DMODEL * DMODEL / 4) / 256, 256, 0, stream>>>(final_w, fw_bf, DMODEL * DMODEL);

    // 3) x_proj (fp32): xdbl = xc @ x_proj_w^T  (M=4096,N=96,K=2048)
    gemm_abt<<<dim3((XPROJ_N + BN - 1) / BN, MROWS / BM), 256, 0, stream>>>(
        xc, x_proj_w, xdbl, nullptr, MROWS, XPROJ_N, DINNER, DINNER, 0);

    // 4) dt_proj (fp32): delta = softplus(dt @ dt_proj_w^T + b)  (K=64, lda=96)
    //    (clobbers x_bf/ipw_bf overlay -- both dead)
    gemm_abt<<<dim3(DINNER / BN, MROWS / BM), 256, 0, stream>>>(
        xdbl, dt_proj_w, delta, dt_proj_b, MROWS, DINNER, DTRANK, XPROJ_N, 2);

    // 5) segmented selective scan + skip + gate -> y_bf (bf16)
    scan_part1<<<dim3(DINNER / 256, SEG, BB), 256, 0, stream>>>(
        delta, xdbl, xc, A_log, hloc, decay);
    scan_combine<<<(BB * DSTATE * DINNER) / 256, 256, 0, stream>>>(
        hloc, decay, hstart);
    scan_part2<<<dim3(DINNER / 256, SEG, BB), 256, 0, stream>>>(
        delta, xdbl, xc, z, A_log, Dvec, hstart, y_bf);

    // 6) out_proj (bf16 MFMA): outb_bf = y @ ssm_out_w^T (M=4096,N=1024,K=2048), bf16 out
    gemm_bf16_mfma<<<dim3(DMODEL / TN, MROWS / TM), 256, 0, stream>>>(
        y_bf, DINNER, sow_bf, DINNER, DINNER,
        outb_bf, nullptr, 1 << 30, DMODEL, nullptr, 0, 1);

    // 7) final (bf16 MFMA): out = silu(outb @ final_w^T + final_b) (M=4096,N=1024,K=1024), f32 out
    gemm_bf16_mfma<<<dim3(DMODEL / TN, MROWS / TM), 256, 0, stream>>>(
        outb_bf, DMODEL, fw_bf, DMODEL, DMODEL,
        out, nullptr, 1 << 30, DMODEL, final_b, 1, 0);
}

// Round 4
// 538.334 us; speedup vs baseline: 5.2538x; 1.1256x over previous
//
#include <hip/hip_runtime.h>
#include <hip/hip_bf16.h>
#include <math.h>

// Problem constants (from reference)
#define BB 2
#define LL 2048
#define DMODEL 1024
#define DINNER 2048
#define DSTATE 16
#define DCONV 4
#define DTRANK 64
#define MROWS (BB * LL)          // 4096
#define XPROJ_N (DTRANK + 2 * DSTATE)  // 96

// scan segmentation
#define SEG 16
#define LS (LL / SEG)            // 128

// x_proj split-K
#define XKSPLIT 8
#define XKC (DINNER / XKSPLIT)   // 256

typedef unsigned short ushort_t;
typedef short s8v __attribute__((ext_vector_type(8)));   // 8 x bf16 (4 VGPRs)
typedef float f4v __attribute__((ext_vector_type(4)));   // 4 x fp32 acc

__device__ __forceinline__ float siluf(float x) {
    return x / (1.f + expf(-x));
}
__device__ __forceinline__ float softplusf(float x) {
    return fmaxf(x, 0.f) + log1pf(expf(-fabsf(x)));
}
__device__ __forceinline__ ushort_t f32_to_bf16(float f) {
    unsigned u = __builtin_bit_cast(unsigned, f);
    unsigned r = (u + 0x7FFFu + ((u >> 16) & 1u)) >> 16;   // RNE
    return (ushort_t)r;
}

// -------------------------------------------------------------------------
// cast fp32 -> bf16, 4 elems/thread
// -------------------------------------------------------------------------
__global__ __launch_bounds__(256) void cast_bf16_kernel(
    const float* __restrict__ in, ushort_t* __restrict__ outp, int n)
{
    const int i = (blockIdx.x * 256 + threadIdx.x) * 4;
    if (i >= n) return;
    const float4 v = *reinterpret_cast<const float4*>(in + i);
    ushort_t o[4] = {f32_to_bf16(v.x), f32_to_bf16(v.y),
                     f32_to_bf16(v.z), f32_to_bf16(v.w)};
    *reinterpret_cast<uint2*>(outp + i) = *reinterpret_cast<uint2*>(o);
}

__global__ __launch_bounds__(256) void zero_f4_kernel(float4* __restrict__ p, int n4)
{
    const int i = blockIdx.x * 256 + threadIdx.x;
    if (i < n4) p[i] = make_float4(0.f, 0.f, 0.f, 0.f);
}

// cast xdbl[:, 0:64] (ld 96, fp32) -> dt_bf [MROWS,64]
__global__ __launch_bounds__(256) void cast_dt_kernel(
    const float* __restrict__ xdbl, ushort_t* __restrict__ dtbf)
{
    const int i4 = (blockIdx.x * 256 + threadIdx.x) * 4;   // over MROWS*64
    const int row = i4 >> 6;
    const int col = i4 & 63;
    const float4 v = *reinterpret_cast<const float4*>(&xdbl[(size_t)row * XPROJ_N + col]);
    ushort_t o[4] = {f32_to_bf16(v.x), f32_to_bf16(v.y),
                     f32_to_bf16(v.z), f32_to_bf16(v.w)};
    *reinterpret_cast<uint2*>(dtbf + i4) = *reinterpret_cast<uint2*>(o);
}

// -------------------------------------------------------------------------
// bf16 MFMA GEMM: C[M,N] = act( A[M,K] @ B[N,K]^T + bias[N] )
// 128x128 tile, BK=32, 256 threads = 4 waves, each wave 64x64 via 4x4
// mfma_f32_16x16x32_bf16. global_load_lds width-16 staging (m97 structure).
// Split output: cols >= splitN go to C1 at (col - splitN). store_bf16
// selects f32 vs bf16 output element type. act: 0 none, 1 silu, 2 softplus.
// -------------------------------------------------------------------------
#define TM 128
#define TN 128
#define TBK 32

__global__ __launch_bounds__(256) void gemm_bf16_mfma(
    const ushort_t* __restrict__ A, int lda,
    const ushort_t* __restrict__ B, int ldb,
    int K,
    void* __restrict__ C0v, void* __restrict__ C1v, int splitN, int ldc,
    const float* __restrict__ bias, int act, int store_bf16)
{
    __shared__ __align__(16) ushort_t As[TM * TBK];   // 8 KB
    __shared__ __align__(16) ushort_t Bs[TN * TBK];   // 8 KB

    const int tid  = threadIdx.x;
    const int lane = tid & 63;
    const int w    = tid >> 6;            // wave 0..3
    const int wm   = w & 1, wn = w >> 1;  // 2x2 wave grid
    const int m0   = blockIdx.y * TM;
    const int n0   = blockIdx.x * TN;

    const int srow = lane >> 2;           // 0..15
    const int scol = (lane & 3) * 8;      // bf16 elems: 0,8,16,24

    f4v acc[4][4] = {};

    for (int k0 = 0; k0 < K; k0 += TBK) {
        #pragma unroll
        for (int t = 0; t < 2; ++t) {
            const int i = w * 2 + t;      // chunk 0..7 -> rows i*16..i*16+15
            const ushort_t* ga = A + (size_t)(m0 + i * 16 + srow) * lda + k0 + scol;
            __builtin_amdgcn_global_load_lds(
                (const __attribute__((address_space(1))) unsigned int*)ga,
                (__attribute__((address_space(3))) unsigned int*)(As + i * 512),
                16, 0, 0);
            const ushort_t* gb = B + (size_t)(n0 + i * 16 + srow) * ldb + k0 + scol;
            __builtin_amdgcn_global_load_lds(
                (const __attribute__((address_space(1))) unsigned int*)gb,
                (__attribute__((address_space(3))) unsigned int*)(Bs + i * 512),
                16, 0, 0);
        }
        __syncthreads();

        const int fr = lane & 15;
        const int kg = lane >> 4;         // k-group 0..3 (8 elems each)
        s8v a[4], b[4];
        #pragma unroll
        for (int t = 0; t < 4; ++t) {
            a[t] = *reinterpret_cast<const s8v*>(As + (wm * 64 + t * 16 + fr) * TBK + kg * 8);
            b[t] = *reinterpret_cast<const s8v*>(Bs + (wn * 64 + t * 16 + fr) * TBK + kg * 8);
        }
        #pragma unroll
        for (int i = 0; i < 4; ++i)
            #pragma unroll
            for (int j = 0; j < 4; ++j)
                acc[i][j] = __builtin_amdgcn_mfma_f32_16x16x32_bf16(
                    a[i], b[j], acc[i][j], 0, 0, 0);
        __syncthreads();
    }

    // epilogue: C/D layout col=lane&15, row=(lane>>4)*4+reg  [m89]
    const int rbase = (lane >> 4) * 4;
    const int cbase = lane & 15;
    #pragma unroll
    for (int i = 0; i < 4; ++i) {
        #pragma unroll
        for (int j = 0; j < 4; ++j) {
            const int row = m0 + wm * 64 + i * 16 + rbase;
            const int col = n0 + wn * 64 + j * 16 + cbase;
            void* Cp = C0v;
            int c2 = col;
            if (C1v && col >= splitN) { Cp = C1v; c2 = col - splitN; }
            const float bv = bias ? bias[col] : 0.f;
            #pragma unroll
            for (int r = 0; r < 4; ++r) {
                float v = acc[i][j][r] + bv;
                if (act == 1) v = siluf(v);
                else if (act == 2) v = softplusf(v);
                if (store_bf16)
                    ((ushort_t*)Cp)[(size_t)(row + r) * ldc + c2] = f32_to_bf16(v);
                else
                    ((float*)Cp)[(size_t)(row + r) * ldc + c2] = v;
            }
        }
    }
}

// -------------------------------------------------------------------------
// x_proj skinny GEMM, split-K with fp32 atomic reduction.
// xdbl[M,96] += xc_bf[M,2048] @ xpw_bf[96,2048]^T  (xdbl pre-zeroed)
// grid (XKSPLIT, M/64); wave w handles rows m0+w*16..+15, all 96 cols.
// -------------------------------------------------------------------------
__global__ __launch_bounds__(256) void xproj_mfma(
    const ushort_t* __restrict__ A, const ushort_t* __restrict__ Bw,
    float* __restrict__ Cout)
{
    __shared__ __align__(16) ushort_t As[64 * 32];   // 4 KB
    __shared__ __align__(16) ushort_t Bs[96 * 32];   // 6 KB

    const int tid = threadIdx.x;
    const int lane = tid & 63;
    const int w = tid >> 6;
    const int kbase = blockIdx.x * XKC;
    const int m0 = blockIdx.y * 64;

    const int srow = lane >> 2;
    const int scol = (lane & 3) * 8;

    f4v acc[6] = {};

    for (int k0 = kbase; k0 < kbase + XKC; k0 += 32) {
        {   // A rows w*16..w*16+15
            const ushort_t* ga = A + (size_t)(m0 + w * 16 + srow) * DINNER + k0 + scol;
            __builtin_amdgcn_global_load_lds(
                (const __attribute__((address_space(1))) unsigned int*)ga,
                (__attribute__((address_space(3))) unsigned int*)(As + (w * 16) * 32),
                16, 0, 0);
        }
        {   // B rows w*16..w*16+15
            const ushort_t* gb = Bw + (size_t)(w * 16 + srow) * DINNER + k0 + scol;
            __builtin_amdgcn_global_load_lds(
                (const __attribute__((address_space(1))) unsigned int*)gb,
                (__attribute__((address_space(3))) unsigned int*)(Bs + (w * 16) * 32),
                16, 0, 0);
        }
        if (w < 2) {   // B rows 64..95
            const ushort_t* gb = Bw + (size_t)((4 + w) * 16 + srow) * DINNER + k0 + scol;
            __builtin_amdgcn_global_load_lds(
                (const __attribute__((address_space(1))) unsigned int*)gb,
                (__attribute__((address_space(3))) unsigned int*)(Bs + ((4 + w) * 16) * 32),
                16, 0, 0);
        }
        __syncthreads();

        const int fr = lane & 15;
        const int kg = lane >> 4;
        const s8v a = *reinterpret_cast<const s8v*>(As + (w * 16 + fr) * 32 + kg * 8);
        #pragma unroll
        for (int j = 0; j < 6; ++j) {
            const s8v b = *reinterpret_cast<const s8v*>(Bs + (j * 16 + fr) * 32 + kg * 8);
            acc[j] = __builtin_amdgcn_mfma_f32_16x16x32_bf16(a, b, acc[j], 0, 0, 0);
        }
        __syncthreads();
    }

    const int rbase = (lane >> 4) * 4;
    const int cb = lane & 15;
    #pragma unroll
    for (int j = 0; j < 6; ++j)
        #pragma unroll
        for (int r = 0; r < 4; ++r)
            atomicAdd(&Cout[(size_t)(m0 + w * 16 + rbase + r) * XPROJ_N + j * 16 + cb],
                      acc[j][r]);
}

// -------------------------------------------------------------------------
// Causal depthwise conv1d (W=4) + bias + SiLU; emits fp32 xc and bf16 xc_bf.
// -------------------------------------------------------------------------
__global__ __launch_bounds__(256) void conv_silu_kernel(
    const float* __restrict__ xin, const float* __restrict__ w,
    const float* __restrict__ b, float* __restrict__ xc,
    ushort_t* __restrict__ xcbf)
{
    const int idx = blockIdx.x * blockDim.x + threadIdx.x;
    const int c = idx % DINNER;
    const int bl = idx / DINNER;
    const int l = bl % LL;
    const int bb = bl / LL;
    if (bb >= BB) return;

    const float* xp = xin + (size_t)bb * LL * DINNER + c;
    float acc = b[c];
    #pragma unroll
    for (int k = 0; k < DCONV; ++k) {
        const int ll = l - (DCONV - 1) + k;
        if (ll >= 0)
            acc = fmaf(xp[(size_t)ll * DINNER], w[c * DCONV + k], acc);
    }
    const float v = siluf(acc);
    xc[idx] = v;
    xcbf[idx] = f32_to_bf16(v);
}

// -------------------------------------------------------------------------
// Segmented selective scan (round-1 design).
// -------------------------------------------------------------------------
__global__ __launch_bounds__(256) void scan_part1(
    const float* __restrict__ delta, const float* __restrict__ xdbl,
    const float* __restrict__ xc, const float* __restrict__ A_log,
    float* __restrict__ hloc, float* __restrict__ decay)
{
    const int d = blockIdx.x * 256 + threadIdx.x;
    const int seg = blockIdx.y;
    const int b = blockIdx.z;
    const int t0 = seg * LS;

    float Ad[DSTATE];
    #pragma unroll
    for (int n = 0; n < DSTATE; ++n)
        Ad[n] = -expf(A_log[d * DSTATE + n]);

    float h[DSTATE];
    #pragma unroll
    for (int n = 0; n < DSTATE; ++n) h[n] = 0.f;

    const float* dp = delta + ((size_t)b * LL) * DINNER + d;
    const float* up = xc    + ((size_t)b * LL) * DINNER + d;
    const float* xb = xdbl  + ((size_t)b * LL) * XPROJ_N;

    float sum_dl = 0.f;
    for (int t = t0; t < t0 + LS; ++t) {
        const float dl = dp[(size_t)t * DINNER];
        const float u  = up[(size_t)t * DINNER];
        const float4 b0 = *reinterpret_cast<const float4*>(&xb[t * XPROJ_N + DTRANK + 0]);
        const float4 b1 = *reinterpret_cast<const float4*>(&xb[t * XPROJ_N + DTRANK + 4]);
        const float4 b2 = *reinterpret_cast<const float4*>(&xb[t * XPROJ_N + DTRANK + 8]);
        const float4 b3 = *reinterpret_cast<const float4*>(&xb[t * XPROJ_N + DTRANK + 12]);
        const float Bv[DSTATE] = {b0.x, b0.y, b0.z, b0.w, b1.x, b1.y, b1.z, b1.w,
                                  b2.x, b2.y, b2.z, b2.w, b3.x, b3.y, b3.z, b3.w};
        const float dlu = dl * u;
        sum_dl += dl;
        #pragma unroll
        for (int n = 0; n < DSTATE; ++n)
            h[n] = __expf(dl * Ad[n]) * h[n] + dlu * Bv[n];
    }

    const size_t base = (((size_t)b * SEG + seg) * DSTATE) * DINNER + d;
    #pragma unroll
    for (int n = 0; n < DSTATE; ++n) {
        hloc[base + (size_t)n * DINNER]  = h[n];
        decay[base + (size_t)n * DINNER] = __expf(Ad[n] * sum_dl);
    }
}

__global__ __launch_bounds__(256) void scan_combine(
    const float* __restrict__ hloc, const float* __restrict__ decay,
    float* __restrict__ hstart)
{
    const int idx = blockIdx.x * 256 + threadIdx.x;
    const int d = idx % DINNER;
    const int n = (idx / DINNER) % DSTATE;
    const int b = idx / (DINNER * DSTATE);
    if (b >= BB) return;

    float carry = 0.f;
    for (int s = 0; s < SEG; ++s) {
        const size_t off = (((size_t)b * SEG + s) * DSTATE + n) * DINNER + d;
        hstart[off] = carry;
        carry = decay[off] * carry + hloc[off];
    }
}

__global__ __launch_bounds__(256) void scan_part2(
    const float* __restrict__ delta, const float* __restrict__ xdbl,
    const float* __restrict__ xc, const float* __restrict__ z,
    const float* __restrict__ A_log, const float* __restrict__ Dvec,
    const float* __restrict__ hstart, ushort_t* __restrict__ ybf)
{
    const int d = blockIdx.x * 256 + threadIdx.x;
    const int seg = blockIdx.y;
    const int b = blockIdx.z;
    const int t0 = seg * LS;

    float Ad[DSTATE];
    #pragma unroll
    for (int n = 0; n < DSTATE; ++n)
        Ad[n] = -expf(A_log[d * DSTATE + n]);

    float h[DSTATE];
    const size_t hbase = (((size_t)b * SEG + seg) * DSTATE) * DINNER + d;
    #pragma unroll
    for (int n = 0; n < DSTATE; ++n)
        h[n] = hstart[hbase + (size_t)n * DINNER];

    const float Dd = Dvec[d];
    const float* dp = delta + ((size_t)b * LL) * DINNER + d;
    const float* up = xc    + ((size_t)b * LL) * DINNER + d;
    const float* xb = xdbl  + ((size_t)b * LL) * XPROJ_N;
    const float* zp = z     + ((size_t)b * LL) * DINNER + d;
    ushort_t*    yp = ybf   + ((size_t)b * LL) * DINNER + d;

    for (int t = t0; t < t0 + LS; ++t) {
        const float dl = dp[(size_t)t * DINNER];
        const float u  = up[(size_t)t * DINNER];
        const float zv = zp[(size_t)t * DINNER];
        const float4 b0 = *reinterpret_cast<const float4*>(&xb[t * XPROJ_N + DTRANK + 0]);
        const float4 b1 = *reinterpret_cast<const float4*>(&xb[t * XPROJ_N + DTRANK + 4]);
        const float4 b2 = *reinterpret_cast<const float4*>(&xb[t * XPROJ_N + DTRANK + 8]);
        const float4 b3 = *reinterpret_cast<const float4*>(&xb[t * XPROJ_N + DTRANK + 12]);
        const float4 c0 = *reinterpret_cast<const float4*>(&xb[t * XPROJ_N + DTRANK + DSTATE + 0]);
        const float4 c1 = *reinterpret_cast<const float4*>(&xb[t * XPROJ_N + DTRANK + DSTATE + 4]);
        const float4 c2 = *reinterpret_cast<const float4*>(&xb[t * XPROJ_N + DTRANK + DSTATE + 8]);
        const float4 c3 = *reinterpret_cast<const float4*>(&xb[t * XPROJ_N + DTRANK + DSTATE + 12]);
        const float Bv[DSTATE] = {b0.x, b0.y, b0.z, b0.w, b1.x, b1.y, b1.z, b1.w,
                                  b2.x, b2.y, b2.z, b2.w, b3.x, b3.y, b3.z, b3.w};
        const float Cv[DSTATE] = {c0.x, c0.y, c0.z, c0.w, c1.x, c1.y, c1.z, c1.w,
                                  c2.x, c2.y, c2.z, c2.w, c3.x, c3.y, c3.z, c3.w};
        const float dlu = dl * u;
        float y = 0.f;
        #pragma unroll
        for (int n = 0; n < DSTATE; ++n) {
            h[n] = __expf(dl * Ad[n]) * h[n] + dlu * Bv[n];
            y = fmaf(h[n], Cv[n], y);
        }
        yp[(size_t)t * DINNER] = f32_to_bf16((y + u * Dd) * siluf(zv));
    }
}

// -------------------------------------------------------------------------
extern "C" void kernel_launch(void* const* d_in, const int* in_sizes, int n_in,
                              void* d_out, int out_size, void* d_ws, size_t ws_size,
                              hipStream_t stream) {
    const float* x         = (const float*)d_in[0];
    const float* in_proj_w = (const float*)d_in[1];
    const float* conv_w    = (const float*)d_in[2];
    const float* conv_b    = (const float*)d_in[3];
    const float* x_proj_w  = (const float*)d_in[4];
    const float* dt_proj_w = (const float*)d_in[5];
    const float* dt_proj_b = (const float*)d_in[6];
    const float* A_log     = (const float*)d_in[7];
    const float* Dvec      = (const float*)d_in[8];
    const float* ssm_out_w = (const float*)d_in[9];
    const float* final_w   = (const float*)d_in[10];
    const float* final_b   = (const float*)d_in[11];
    float* out = (float*)d_out;

    // ---- workspace layout (<= 144 MB; round-1 proved >= 145.5 MB exists) ----
    const size_t MB = 1024 * 1024;
    char* base = (char*)d_ws;
    float* xin   = (float*)(base);             // 32 MB [in_proj -> conv]
    float* z     = (float*)(base + 32 * MB);   // 32 MB [in_proj -> scan_part2]
    float* xc    = (float*)(base + 64 * MB);   // 32 MB [conv -> scan_part2]
    float* xdbl  = (float*)(base + 96 * MB);   // 1.5 MB [x_proj -> scan]
    float* delta = (float*)(base + 98 * MB);   // 32 MB [dt_proj -> scan_part2]
    float* hloc  = (float*)(base + 130 * MB);  // 4 MB scan scratch
    float* decay = (float*)(base + 134 * MB);  // 4 MB
    float* hstart= (float*)(base + 138 * MB);  // 4 MB
    // small bf16 buffers, own space:
    ushort_t* xpw_bf = (ushort_t*)(base + 142 * MB);            // 384 KB
    ushort_t* dtw_bf = (ushort_t*)(base + 142 * MB + 512 * 1024);  // 256 KB
    ushort_t* dt_bf  = (ushort_t*)(base + 143 * MB);            // 512 KB
    // overlays on delta (dead until dt_proj):
    ushort_t* x_bf   = (ushort_t*)(base + 98 * MB);        // 8 MB [-> in_proj]
    ushort_t* ipw_bf = (ushort_t*)(base + 106 * MB);       // 8 MB [-> in_proj]
    ushort_t* xc_bf  = (ushort_t*)(base + 114 * MB);       // 16 MB [conv -> x_proj]
    // overlays on xin (dead after conv):
    ushort_t* y_bf    = (ushort_t*)(base);                 // 16 MB [scan_part2 -> out_proj]
    ushort_t* outb_bf = (ushort_t*)(base + 16 * MB);       // 8 MB [out_proj -> final]
    ushort_t* sow_bf  = (ushort_t*)(base + 24 * MB);       // 4 MB [cast -> out_proj]
    ushort_t* fw_bf   = (ushort_t*)(base + 28 * MB);       // 2 MB [cast -> final]

    // 0) casts for in_proj
    cast_bf16_kernel<<<(MROWS * DMODEL / 4) / 256, 256, 0, stream>>>(x, x_bf, MROWS * DMODEL);
    cast_bf16_kernel<<<(2 * DINNER * DMODEL / 4) / 256, 256, 0, stream>>>(in_proj_w, ipw_bf, 2 * DINNER * DMODEL);

    // 1) in_proj (bf16 MFMA): [xin | z] = x @ in_proj_w^T  (M=4096,N=4096,K=1024)
    gemm_bf16_mfma<<<dim3(2 * DINNER / TN, MROWS / TM), 256, 0, stream>>>(
        x_bf, DMODEL, ipw_bf, DMODEL, DMODEL,
        xin, z, DINNER, DINNER, nullptr, 0, 0);

    // 2) causal depthwise conv + SiLU -> xc (fp32) + xc_bf (bf16)
    conv_silu_kernel<<<(MROWS * DINNER) / 256, 256, 0, stream>>>(
        xin, conv_w, conv_b, xc, xc_bf);

    // 2b) small weight casts (xin region + tail region)
    cast_bf16_kernel<<<(DMODEL * DINNER / 4) / 256, 256, 0, stream>>>(ssm_out_w, sow_bf, DMODEL * DINNER);
    cast_bf16_kernel<<<(DMODEL * DMODEL / 4) / 256, 256, 0, stream>>>(final_w, fw_bf, DMODEL * DMODEL);
    cast_bf16_kernel<<<(XPROJ_N * DINNER / 4) / 256, 256, 0, stream>>>(x_proj_w, xpw_bf, XPROJ_N * DINNER);
    cast_bf16_kernel<<<(DINNER * DTRANK / 4) / 256, 256, 0, stream>>>(dt_proj_w, dtw_bf, DINNER * DTRANK);

    // 3) x_proj (bf16 MFMA, split-K atomic): xdbl = xc @ x_proj_w^T (M=4096,N=96,K=2048)
    zero_f4_kernel<<<(MROWS * XPROJ_N / 4 + 255) / 256, 256, 0, stream>>>(
        (float4*)xdbl, MROWS * XPROJ_N / 4);
    xproj_mfma<<<dim3(XKSPLIT, MROWS / 64), 256, 0, stream>>>(xc_bf, xpw_bf, xdbl);

    // 4) dt_proj (bf16 MFMA): delta = softplus(dt @ dt_proj_w^T + b) (M=4096,N=2048,K=64)
    cast_dt_kernel<<<(MROWS * DTRANK / 4) / 256, 256, 0, stream>>>(xdbl, dt_bf);
    gemm_bf16_mfma<<<dim3(DINNER / TN, MROWS / TM), 256, 0, stream>>>(
        dt_bf, DTRANK, dtw_bf, DTRANK, DTRANK,
        delta, nullptr, 1 << 30, DINNER, dt_proj_b, 2, 0);

    // 5) segmented selective scan + skip + gate -> y_bf (bf16)
    scan_part1<<<dim3(DINNER / 256, SEG, BB), 256, 0, stream>>>(
        delta, xdbl, xc, A_log, hloc, decay);
    scan_combine<<<(BB * DSTATE * DINNER) / 256, 256, 0, stream>>>(
        hloc, decay, hstart);
    scan_part2<<<dim3(DINNER / 256, SEG, BB), 256, 0, stream>>>(
        delta, xdbl, xc, z, A_log, Dvec, hstart, y_bf);

    // 6) out_proj (bf16 MFMA): outb_bf = y @ ssm_out_w^T (M=4096,N=1024,K=2048), bf16 out
    gemm_bf16_mfma<<<dim3(DMODEL / TN, MROWS / TM), 256, 0, stream>>>(
        y_bf, DINNER, sow_bf, DINNER, DINNER,
        outb_bf, nullptr, 1 << 30, DMODEL, nullptr, 0, 1);

    // 7) final (bf16 MFMA): out = silu(outb @ final_w^T + final_b) (M=4096,N=1024,K=1024), f32 out
    gemm_bf16_mfma<<<dim3(DMODEL / TN, MROWS / TM), 256, 0, stream>>>(
        outb_bf, DMODEL, fw_bf, DMODEL, DMODEL,
        out, nullptr, 1 << 30, DMODEL, final_b, 1, 0);
}